// Round 1
// baseline (330.493 us; speedup 1.0000x reference)
//
#include <hip/hip_runtime.h>
#include <hip/hip_bf16.h>

#define B_N 8192
#define D_DIM 1024

using bf16 = __hip_bfloat16;
typedef float f32x4 __attribute__((ext_vector_type(4)));
typedef __bf16 bf16x8 __attribute__((ext_vector_type(8)));

// ws layout:
//   [0, 16MB)            : Xn bf16 [8192][1024]
//   16MB + 0     .. 32KB : S[8192]  f32  (sum exp(sim-10), j != i)
//   16MB + 32KB  .. 64KB : M[8192]  f32  (sum mask*sim)
//   16MB + 64KB  .. 96KB : P[8192]  f32  (count mask)
//   16MB + 96KB          : flag u32 (mask-dtype detection)

__global__ void detect_mask_kernel(const unsigned* __restrict__ m, unsigned* __restrict__ flag) {
    // Read first 64MB as u32. If mask is 1-byte bool, many words are >1
    // (e.g. 0x00010000). If mask is int32 0/1, no word exceeds 1.
    unsigned c = 0;
    for (size_t i = (size_t)blockIdx.x * blockDim.x + threadIdx.x; i < (size_t)16777216;
         i += (size_t)gridDim.x * blockDim.x) {
        c += (m[i] > 1u) ? 1u : 0u;
    }
    for (int s = 1; s < 64; s <<= 1) c += __shfl_xor(c, s, 64);
    if ((threadIdx.x & 63) == 0 && c) atomicAdd(flag, c);
}

__global__ void normalize_kernel(const float* __restrict__ emb, bf16* __restrict__ xn) {
    int row = blockIdx.x;
    int t = threadIdx.x;  // 256 threads, 4 floats each
    const float4* src = (const float4*)(emb + (size_t)row * D_DIM);
    float4 v = src[t];
    float ss = v.x * v.x + v.y * v.y + v.z * v.z + v.w * v.w;
    for (int s = 1; s < 64; s <<= 1) ss += __shfl_xor(ss, s, 64);
    __shared__ float wss[4];
    if ((t & 63) == 0) wss[t >> 6] = ss;
    __syncthreads();
    float tot = wss[0] + wss[1] + wss[2] + wss[3];
    float scale = 1.0f / fmaxf(sqrtf(tot), 1e-12f);
    ushort4 o;
    o.x = __builtin_bit_cast(unsigned short, __float2bfloat16(v.x * scale));
    o.y = __builtin_bit_cast(unsigned short, __float2bfloat16(v.y * scale));
    o.z = __builtin_bit_cast(unsigned short, __float2bfloat16(v.z * scale));
    o.w = __builtin_bit_cast(unsigned short, __float2bfloat16(v.w * scale));
    *reinterpret_cast<ushort4*>(xn + (size_t)row * D_DIM + t * 4) = o;
}

// 128x128 tile, BK=64, 4 waves (2x2), each wave 64x64 = 4x4 frags of 16x16x32.
__global__ __launch_bounds__(256, 2) void sim_kernel(
    const bf16* __restrict__ xn,
    const unsigned char* __restrict__ mask8,
    const int* __restrict__ mask32,
    const unsigned* __restrict__ flag,
    float* __restrict__ S, float* __restrict__ M, float* __restrict__ P)
{
    __shared__ bf16 Abuf[128 * 64];
    __shared__ bf16 Bbuf[128 * 64];

    int b0 = blockIdx.x;
    int tile = ((b0 & 7) << 9) | (b0 >> 3);  // XCD swizzle (4096 % 8 == 0, bijective)
    int by = tile >> 6, bx = tile & 63;
    int t = threadIdx.x;
    int w = t >> 6, lane = t & 63;
    int wm = w >> 1, wn = w & 1;
    int l15 = lane & 15, lg = lane >> 4;

    const bool is_u8 = (*flag != 0u);

    f32x4 acc[4][4];
#pragma unroll
    for (int i = 0; i < 4; i++)
#pragma unroll
        for (int j = 0; j < 4; j++) acc[i][j] = {0.f, 0.f, 0.f, 0.f};

    int arow0 = by << 7;
    int brow0 = bx << 7;

    for (int kt = 0; kt < D_DIM; kt += 64) {
        // stage A,B tiles (128x64 bf16 = 16KB each), linear LDS, width-16 async
#pragma unroll
        for (int i = 0; i < 4; ++i) {
            int ebase = i * 256 + w * 64;     // wave-uniform
            int e = ebase + lane;             // element-of-8 index
            int r = e >> 3, c8 = (e & 7) << 3;
            const bf16* gA = xn + (size_t)(arow0 + r) * D_DIM + kt + c8;
            const bf16* gB = xn + (size_t)(brow0 + r) * D_DIM + kt + c8;
            char* lA = (char*)Abuf + (size_t)ebase * 16;
            char* lB = (char*)Bbuf + (size_t)ebase * 16;
            __builtin_amdgcn_global_load_lds((const __attribute__((address_space(1))) void*)gA,
                                             (__attribute__((address_space(3))) void*)lA, 16, 0, 0);
            __builtin_amdgcn_global_load_lds((const __attribute__((address_space(1))) void*)gB,
                                             (__attribute__((address_space(3))) void*)lB, 16, 0, 0);
        }
        __syncthreads();
#pragma unroll
        for (int kk = 0; kk < 2; ++kk) {
            bf16x8 a[4], b[4];
#pragma unroll
            for (int f = 0; f < 4; ++f) {
                a[f] = *reinterpret_cast<const bf16x8*>(Abuf + (wm * 64 + f * 16 + l15) * 64 + kk * 32 + lg * 8);
                b[f] = *reinterpret_cast<const bf16x8*>(Bbuf + (wn * 64 + f * 16 + l15) * 64 + kk * 32 + lg * 8);
            }
#pragma unroll
            for (int fm = 0; fm < 4; ++fm)
#pragma unroll
                for (int fn = 0; fn < 4; ++fn)
                    acc[fm][fn] = __builtin_amdgcn_mfma_f32_16x16x32_bf16(a[fm], b[fn], acc[fm][fn], 0, 0, 0);
        }
        __syncthreads();
    }

    // Epilogue: per-row { sum exp(sim-10) (j!=i), sum mask*sim, count mask }
    // C/D layout: col = lane&15, row = lg*4 + reg  (m89-verified)
#pragma unroll
    for (int fm = 0; fm < 4; ++fm) {
#pragma unroll
        for (int reg = 0; reg < 4; ++reg) {
            int gr = arow0 + wm * 64 + fm * 16 + lg * 4 + reg;
            float E = 0.f, Ms = 0.f, Pc = 0.f;
#pragma unroll
            for (int fn = 0; fn < 4; ++fn) {
                int gc = brow0 + wn * 64 + fn * 16 + l15;
                float sim = acc[fm][fn][reg] * 10.0f;
                if (gr != gc) E += __expf(sim - 10.0f);
                size_t mi = (size_t)gr * B_N + gc;
                int mb = is_u8 ? (int)mask8[mi] : mask32[mi];
                if (mb) { Ms += sim; Pc += 1.0f; }
            }
            for (int s = 1; s < 16; s <<= 1) {
                E  += __shfl_xor(E, s, 64);
                Ms += __shfl_xor(Ms, s, 64);
                Pc += __shfl_xor(Pc, s, 64);
            }
            if (l15 == 0) {
                atomicAdd(&S[gr], E);
                atomicAdd(&M[gr], Ms);
                atomicAdd(&P[gr], Pc);
            }
        }
    }
}

__global__ void finalize_kernel(const float* __restrict__ S, const float* __restrict__ M,
                                const float* __restrict__ P, float* __restrict__ out) {
    int t = threadIdx.x;  // 1024
    double a = 0.0;
    for (int i = t; i < B_N; i += 1024) {
        float lse = 10.0f + logf(S[i]);
        a += (double)P[i] * (double)lse - (double)M[i];
    }
    for (int s = 1; s < 64; s <<= 1) a += __shfl_xor(a, s, 64);
    __shared__ double sh[16];
    if ((t & 63) == 0) sh[t >> 6] = a;
    __syncthreads();
    if (t == 0) {
        double tot = 0.0;
        for (int i = 0; i < 16; ++i) tot += sh[i];
        out[0] = (float)(tot / (double)B_N);
    }
}

extern "C" void kernel_launch(void* const* d_in, const int* in_sizes, int n_in,
                              void* d_out, int out_size, void* d_ws, size_t ws_size,
                              hipStream_t stream) {
    const float* emb = (const float*)d_in[0];
    const void* mask = d_in[1];
    char* ws = (char*)d_ws;
    bf16* xn = (bf16*)ws;
    const size_t XN_BYTES = (size_t)B_N * D_DIM * 2;  // 16MB
    float* S = (float*)(ws + XN_BYTES);
    float* M = (float*)(ws + XN_BYTES + 32768);
    float* P = (float*)(ws + XN_BYTES + 65536);
    unsigned* flag = (unsigned*)(ws + XN_BYTES + 98304);

    hipMemsetAsync(ws + XN_BYTES, 0, 98304 + 16, stream);
    detect_mask_kernel<<<1024, 256, 0, stream>>>((const unsigned*)mask, flag);
    normalize_kernel<<<B_N, 256, 0, stream>>>(emb, xn);
    sim_kernel<<<4096, 256, 0, stream>>>(xn, (const unsigned char*)mask, (const int*)mask,
                                         flag, S, M, P);
    finalize_kernel<<<1, 1024, 0, stream>>>(S, M, P, (float*)d_out);
}

// Round 2
// 253.938 us; speedup vs baseline: 1.3015x; 1.3015x over previous
//
#include <hip/hip_runtime.h>
#include <hip/hip_bf16.h>
#include <math.h>

#define B_N 8192
#define D_DIM 1024
#define NWORDS 128  // u64 words per mask row

using bf16 = __hip_bfloat16;
typedef float f32x4 __attribute__((ext_vector_type(4)));
typedef __bf16 bf16x8 __attribute__((ext_vector_type(8)));

// ws layout:
//   [0, 16MB)                : Xn bf16 [8192][1024]
//   [16MB, 24MB)             : maskbits u64 [8192][128]
//   24MB + 0     .. 32KB     : S[8192]  f32  (sum exp(sim-10), j != i)
//   24MB + 32KB  .. 64KB     : M[8192]  f32  (sum mask*sim)
//   24MB + 64KB  .. 96KB     : P[8192]  f32  (count mask)
//   24MB + 96KB              : flag u32 (mask-dtype detection)

__global__ void detect_mask_kernel(const unsigned* __restrict__ m, unsigned* __restrict__ flag) {
    // Read first 1MB as u32. u8-bool mask at ~1% density -> ~3% of words >1.
    // i32 mask -> all words in {0,1} -> flag stays 0.
    unsigned c = 0;
    for (int i = blockIdx.x * blockDim.x + threadIdx.x; i < 262144;
         i += gridDim.x * blockDim.x) {
        c += (m[i] > 1u) ? 1u : 0u;
    }
    for (int s = 1; s < 64; s <<= 1) c += __shfl_xor(c, s, 64);
    if ((threadIdx.x & 63) == 0 && c) atomicAdd(flag, c);
}

__global__ void pack_mask_kernel(const unsigned char* __restrict__ m8,
                                 const int* __restrict__ m32,
                                 const unsigned* __restrict__ flag,
                                 unsigned long long* __restrict__ bits) {
    const bool is_u8 = (*flag != 0u);
    int lane = threadIdx.x & 63;
    size_t gw = ((size_t)blockIdx.x * blockDim.x + threadIdx.x) >> 6;
    size_t nwaves = ((size_t)gridDim.x * blockDim.x) >> 6;
    const size_t nw = (size_t)B_N * NWORDS;  // 1,048,576 words
    for (size_t w = gw; w < nw; w += nwaves) {
        bool v;
        if (is_u8) v = m8[w * 64 + lane] != 0;
        else       v = m32[w * 64 + lane] != 0;
        unsigned long long b = __ballot(v);
        if (lane == 0) bits[w] = b;
    }
}

__global__ void normalize_kernel(const float* __restrict__ emb, bf16* __restrict__ xn) {
    int row = blockIdx.x;
    int t = threadIdx.x;  // 256 threads, 4 floats each
    const float4* src = (const float4*)(emb + (size_t)row * D_DIM);
    float4 v = src[t];
    float ss = v.x * v.x + v.y * v.y + v.z * v.z + v.w * v.w;
    for (int s = 1; s < 64; s <<= 1) ss += __shfl_xor(ss, s, 64);
    __shared__ float wss[4];
    if ((t & 63) == 0) wss[t >> 6] = ss;
    __syncthreads();
    float tot = wss[0] + wss[1] + wss[2] + wss[3];
    float scale = 1.0f / fmaxf(sqrtf(tot), 1e-12f);
    ushort4 o;
    o.x = __builtin_bit_cast(unsigned short, __float2bfloat16(v.x * scale));
    o.y = __builtin_bit_cast(unsigned short, __float2bfloat16(v.y * scale));
    o.z = __builtin_bit_cast(unsigned short, __float2bfloat16(v.z * scale));
    o.w = __builtin_bit_cast(unsigned short, __float2bfloat16(v.w * scale));
    *reinterpret_cast<ushort4*>(xn + (size_t)row * D_DIM + t * 4) = o;
}

// Upper-triangle tiling: 64 diag tiles + 2016 off-diag tiles = 2080 blocks.
// 128x128 tile, BK=64, 4 waves (2x2), each wave 64x64 = 4x4 frags of 16x16x32.
// Off-diag tiles scatter to BOTH row-panel rows (mask[gr][gc]) and
// col-panel rows (mask[gc][gr], reduced across lane-groups).
__global__ __launch_bounds__(256, 2) void sim_kernel(
    const bf16* __restrict__ xn,
    const unsigned long long* __restrict__ mbits,
    float* __restrict__ S, float* __restrict__ M, float* __restrict__ P)
{
    __shared__ bf16 Abuf[128 * 64];
    __shared__ bf16 Bbuf[128 * 64];

    // XCD-aware bijective swizzle (2080 % 8 == 0 -> 260 per XCD)
    int b0 = blockIdx.x;
    int tile = (b0 & 7) * 260 + (b0 >> 3);
    int by, bx;
    bool isdiag;
    if (tile < 64) {
        by = bx = tile;
        isdiag = true;
    } else {
        int j = tile - 64;  // [0, 2016)
        int p = (int)((sqrt((double)(8 * j + 1)) + 1.0) * 0.5);
        while (p * (p - 1) / 2 > j) --p;
        while ((p + 1) * p / 2 <= j) ++p;
        int q = j - p * (p - 1) / 2;
        by = q; bx = p;  // by < bx
        isdiag = false;
    }

    int t = threadIdx.x;
    int w = t >> 6, lane = t & 63;
    int wm = w >> 1, wn = w & 1;
    int l15 = lane & 15, lg = lane >> 4;

    f32x4 acc[4][4];
#pragma unroll
    for (int i = 0; i < 4; i++)
#pragma unroll
        for (int j = 0; j < 4; j++) acc[i][j] = {0.f, 0.f, 0.f, 0.f};

    int arow0 = by << 7;
    int brow0 = bx << 7;

    for (int kt = 0; kt < D_DIM; kt += 64) {
#pragma unroll
        for (int i = 0; i < 4; ++i) {
            int ebase = i * 256 + w * 64;     // wave-uniform
            int e = ebase + lane;             // element-of-8 index
            int r = e >> 3, c8 = (e & 7) << 3;
            const bf16* gA = xn + (size_t)(arow0 + r) * D_DIM + kt + c8;
            const bf16* gB = xn + (size_t)(brow0 + r) * D_DIM + kt + c8;
            char* lA = (char*)Abuf + (size_t)ebase * 16;
            char* lB = (char*)Bbuf + (size_t)ebase * 16;
            __builtin_amdgcn_global_load_lds((const __attribute__((address_space(1))) void*)gA,
                                             (__attribute__((address_space(3))) void*)lA, 16, 0, 0);
            __builtin_amdgcn_global_load_lds((const __attribute__((address_space(1))) void*)gB,
                                             (__attribute__((address_space(3))) void*)lB, 16, 0, 0);
        }
        __syncthreads();
#pragma unroll
        for (int kk = 0; kk < 2; ++kk) {
            bf16x8 a[4], b[4];
#pragma unroll
            for (int f = 0; f < 4; ++f) {
                a[f] = *reinterpret_cast<const bf16x8*>(Abuf + (wm * 64 + f * 16 + l15) * 64 + kk * 32 + lg * 8);
                b[f] = *reinterpret_cast<const bf16x8*>(Bbuf + (wn * 64 + f * 16 + l15) * 64 + kk * 32 + lg * 8);
            }
#pragma unroll
            for (int fm = 0; fm < 4; ++fm)
#pragma unroll
                for (int fn = 0; fn < 4; ++fn)
                    acc[fm][fn] = __builtin_amdgcn_mfma_f32_16x16x32_bf16(a[fm], b[fn], acc[fm][fn], 0, 0, 0);
        }
        __syncthreads();
    }

    // ---- Epilogue ----
    // C/D layout: col = l15, row = lg*4 + reg (within 16x16 frag).
    // Row-side mask word: row gr, cols [brow0 + wn*64, +64) -> word bx*2+wn.
    // Col-side mask word: row gc, cols [arow0 + wm*64, +64) -> word by*2+wm.
    float colE[4] = {0, 0, 0, 0}, colM[4] = {0, 0, 0, 0}, colP[4] = {0, 0, 0, 0};
    unsigned long long wcol[4] = {0, 0, 0, 0};
    if (!isdiag) {
#pragma unroll
        for (int fn = 0; fn < 4; ++fn) {
            int gc = brow0 + wn * 64 + fn * 16 + l15;
            wcol[fn] = mbits[(size_t)gc * NWORDS + by * 2 + wm];
        }
    }

#pragma unroll
    for (int fm = 0; fm < 4; ++fm) {
#pragma unroll
        for (int reg = 0; reg < 4; ++reg) {
            int lr = fm * 16 + lg * 4 + reg;          // row within wave tile
            int gr = arow0 + wm * 64 + lr;
            unsigned long long wrow = mbits[(size_t)gr * NWORDS + bx * 2 + wn];
            float E = 0.f, Ms = 0.f, Pc = 0.f;
#pragma unroll
            for (int fn = 0; fn < 4; ++fn) {
                int lc = wn * 64 + fn * 16 + l15;     // col within block tile
                int gc = brow0 + lc;
                float sim = acc[fm][fn][reg] * 10.0f;
                float e = __expf(sim - 10.0f);
                if (isdiag && gr == gc) e = 0.f;
                E += e;
                if ((wrow >> (fn * 16 + l15)) & 1ull) { Ms += sim; Pc += 1.f; }
                if (!isdiag) {
                    colE[fn] += e;
                    if ((wcol[fn] >> lr) & 1ull) { colM[fn] += sim; colP[fn] += 1.f; }
                }
            }
            for (int s = 1; s < 16; s <<= 1) {
                E  += __shfl_xor(E, s, 64);
                Ms += __shfl_xor(Ms, s, 64);
                Pc += __shfl_xor(Pc, s, 64);
            }
            if (l15 == 0) {
                atomicAdd(&S[gr], E);
                atomicAdd(&M[gr], Ms);
                atomicAdd(&P[gr], Pc);
            }
        }
    }

    if (!isdiag) {
#pragma unroll
        for (int fn = 0; fn < 4; ++fn) {
            float E = colE[fn], Ms = colM[fn], Pc = colP[fn];
            E  += __shfl_xor(E, 16, 64);  Ms += __shfl_xor(Ms, 16, 64);  Pc += __shfl_xor(Pc, 16, 64);
            E  += __shfl_xor(E, 32, 64);  Ms += __shfl_xor(Ms, 32, 64);  Pc += __shfl_xor(Pc, 32, 64);
            if (lg == 0) {
                int gc = brow0 + wn * 64 + fn * 16 + l15;
                atomicAdd(&S[gc], E);
                atomicAdd(&M[gc], Ms);
                atomicAdd(&P[gc], Pc);
            }
        }
    }
}

__global__ void finalize_kernel(const float* __restrict__ S, const float* __restrict__ M,
                                const float* __restrict__ P, float* __restrict__ out) {
    int t = threadIdx.x;  // 1024
    double a = 0.0;
    for (int i = t; i < B_N; i += 1024) {
        float lse = 10.0f + logf(S[i]);
        a += (double)P[i] * (double)lse - (double)M[i];
    }
    for (int s = 1; s < 64; s <<= 1) a += __shfl_xor(a, s, 64);
    __shared__ double sh[16];
    if ((t & 63) == 0) sh[t >> 6] = a;
    __syncthreads();
    if (t == 0) {
        double tot = 0.0;
        for (int i = 0; i < 16; ++i) tot += sh[i];
        out[0] = (float)(tot / (double)B_N);
    }
}

extern "C" void kernel_launch(void* const* d_in, const int* in_sizes, int n_in,
                              void* d_out, int out_size, void* d_ws, size_t ws_size,
                              hipStream_t stream) {
    const float* emb = (const float*)d_in[0];
    const void* mask = d_in[1];
    char* ws = (char*)d_ws;
    bf16* xn = (bf16*)ws;
    const size_t XN_BYTES = (size_t)B_N * D_DIM * 2;              // 16MB
    unsigned long long* mbits = (unsigned long long*)(ws + XN_BYTES);
    const size_t MB_BYTES = (size_t)B_N * NWORDS * 8;             // 8MB
    char* red = ws + XN_BYTES + MB_BYTES;
    float* S = (float*)red;
    float* M = (float*)(red + 32768);
    float* P = (float*)(red + 65536);
    unsigned* flag = (unsigned*)(red + 98304);

    hipMemsetAsync(red, 0, 98304 + 16, stream);
    detect_mask_kernel<<<64, 256, 0, stream>>>((const unsigned*)mask, flag);
    pack_mask_kernel<<<2048, 256, 0, stream>>>((const unsigned char*)mask, (const int*)mask,
                                               flag, mbits);
    normalize_kernel<<<B_N, 256, 0, stream>>>(emb, xn);
    sim_kernel<<<2080, 256, 0, stream>>>(xn, mbits, S, M, P);
    finalize_kernel<<<1, 1024, 0, stream>>>(S, M, P, (float*)d_out);
}